// Round 1
// baseline (320.610 us; speedup 1.0000x reference)
//
#include <hip/hip_runtime.h>

// TensorProduct: out[z, o*U+u] = sum_{p: idx_out[p]==o} coeffs[p] * x0[z, idx0[p]*U+u] * x1[z, idx1[p]*U+u]
// Z=16384, U=128, NSEG=(32,8,32), P=128. All f32. Memory-bound (576 MB compulsory).

#define Z_DIM 16384
#define U_DIM 128
#define NSEG0 32
#define NSEG1 8
#define NSEG2 32
#define P_DIM 128

__global__ __launch_bounds__(256) void tp_kernel(
    const float* __restrict__ x0,
    const float* __restrict__ x1,
    const float* __restrict__ coeffs,
    const int* __restrict__ idx0,
    const int* __restrict__ idx1,
    const int* __restrict__ idx_out,
    float* __restrict__ out)
{
    // --- per-block grouping of the P terms by output segment (counting sort in LDS) ---
    __shared__ int   s_off[NSEG2 + 1];
    __shared__ int   s_pos[NSEG2];
    __shared__ int   s_i0[P_DIM];
    __shared__ int   s_i1[P_DIM];
    __shared__ float s_c [P_DIM];
    __shared__ int   s_raw_o [P_DIM];
    __shared__ int   s_raw_i0[P_DIM];
    __shared__ int   s_raw_i1[P_DIM];
    __shared__ float s_raw_c [P_DIM];

    const int t = threadIdx.x;
    if (t < P_DIM) {               // parallel stage of the tiny index tables
        s_raw_o [t] = idx_out[t];
        s_raw_i0[t] = idx0[t];
        s_raw_i1[t] = idx1[t];
        s_raw_c [t] = coeffs[t];
    }
    __syncthreads();
    if (t == 0) {                  // serial counting sort, all in LDS (no scratch arrays)
        for (int o = 0; o <= NSEG2; ++o) s_off[o] = 0;
        for (int p = 0; p < P_DIM; ++p) s_off[s_raw_o[p] + 1]++;
        for (int o = 0; o < NSEG2; ++o) { s_off[o + 1] += s_off[o]; s_pos[o] = s_off[o]; }
        for (int p = 0; p < P_DIM; ++p) {
            const int o = s_raw_o[p];
            const int d = s_pos[o]++;
            s_i0[d] = s_raw_i0[p];
            s_i1[d] = s_raw_i1[p];
            s_c [d] = s_raw_c [p];
        }
    }
    __syncthreads();

    // --- main compute: one thread per (z, u-quad) ---
    const int gtid = blockIdx.x * 256 + t;
    const int z  = gtid >> 5;            // 32 u-quads per z-row
    const int uq = (gtid & 31) << 2;     // float offset within a segment row

    const float4* x0r = reinterpret_cast<const float4*>(x0 + (size_t)z * (NSEG0 * U_DIM) + uq);
    const float4* x1r = reinterpret_cast<const float4*>(x1 + (size_t)z * (NSEG1 * U_DIM) + uq);
    float4*       our = reinterpret_cast<float4*>      (out + (size_t)z * (NSEG2 * U_DIM) + uq);

    for (int o = 0; o < NSEG2; ++o) {
        float4 acc = make_float4(0.f, 0.f, 0.f, 0.f);
        const int b = s_off[o];
        const int e = s_off[o + 1];
        for (int k = b; k < e; ++k) {
            const int   i0 = s_i0[k];
            const int   i1 = s_i1[k];
            const float c  = s_c [k];
            const float4 a = x0r[i0 * (U_DIM / 4)];
            const float4 v = x1r[i1 * (U_DIM / 4)];
            acc.x = fmaf(c, a.x * v.x, acc.x);
            acc.y = fmaf(c, a.y * v.y, acc.y);
            acc.z = fmaf(c, a.z * v.z, acc.z);
            acc.w = fmaf(c, a.w * v.w, acc.w);
        }
        our[o * (U_DIM / 4)] = acc;      // every segment written (handles empty segs + poisoned d_out)
    }
}

extern "C" void kernel_launch(void* const* d_in, const int* in_sizes, int n_in,
                              void* d_out, int out_size, void* d_ws, size_t ws_size,
                              hipStream_t stream) {
    const float* x0      = (const float*)d_in[0];
    const float* x1      = (const float*)d_in[1];
    const float* coeffs  = (const float*)d_in[2];
    const int*   idx0    = (const int*)d_in[3];
    const int*   idx1    = (const int*)d_in[4];
    const int*   idx_out = (const int*)d_in[5];
    float* out = (float*)d_out;

    // Z * (U/4) threads = 16384 * 32 = 524288 -> 2048 blocks of 256
    const int threads = 256;
    const int blocks  = (Z_DIM * (U_DIM / 4)) / threads;
    tp_kernel<<<blocks, threads, 0, stream>>>(x0, x1, coeffs, idx0, idx1, idx_out, out);
}

// Round 2
// 182.465 us; speedup vs baseline: 1.7571x; 1.7571x over previous
//
#include <hip/hip_runtime.h>

// TensorProduct: out[z, o*U+u] = sum_{p: idx_out[p]==o} coeffs[p] * x0[z, idx0[p]*U+u] * x1[z, idx1[p]*U+u]
// Z=16384, U=128, NSEG=(32,8,32), P=128, all f32.
// Memory-bound: compulsory HBM = 320 MB read + 256 MB write = 576 MB -> ~95 us floor.
// Strategy: stage the block's x0/x1 rows in LDS once (kills the L2-thrash re-reads
// seen in round 1: 880 MB fetched vs 320 MB compulsory), serve the gather from LDS.

#define Z_DIM 16384
#define U_DIM 128
#define NSEG0 32
#define NSEG1 8
#define NSEG2 32
#define P_DIM 128
#define ZPB   2          // z-rows per block
#define BLK   256        // threads per block (128 per z-row, one u each)

__global__ __launch_bounds__(BLK) void tp_kernel(
    const float* __restrict__ x0,
    const float* __restrict__ x1,
    const float* __restrict__ coeffs,
    const int* __restrict__ idx0,
    const int* __restrict__ idx1,
    const int* __restrict__ idx_out,
    float* __restrict__ out)
{
    __shared__ float s_x0[ZPB][NSEG0 * U_DIM];   // 2 * 16 KB = 32 KB
    __shared__ float s_x1[ZPB][NSEG1 * U_DIM];   // 2 *  4 KB =  8 KB
    __shared__ int   s_pack[P_DIM];              // sorted i0 | (i1<<16)
    __shared__ float s_c[P_DIM];                 // sorted coeff
    __shared__ int   s_cnt[NSEG2];
    __shared__ int   s_off[NSEG2];

    const int t = threadIdx.x;

    // --- load this thread's term (indices are tiny, L2-resident) ---
    int my_o = 0, my_i0 = 0, my_i1 = 0;
    float my_c = 0.f;
    if (t < P_DIM) {
        my_o  = idx_out[t];
        my_i0 = idx0[t];
        my_i1 = idx1[t];
        my_c  = coeffs[t];
    }
    if (t < NSEG2) s_cnt[t] = 0;

    // --- stage x0/x1 rows for this block's ZPB z's: contiguous float4 copy ---
    {
        const size_t z0 = (size_t)blockIdx.x * ZPB;
        const float4* g0 = reinterpret_cast<const float4*>(x0 + z0 * (NSEG0 * U_DIM));
        const float4* g1 = reinterpret_cast<const float4*>(x1 + z0 * (NSEG1 * U_DIM));
        float4* l0 = reinterpret_cast<float4*>(&s_x0[0][0]);
        float4* l1 = reinterpret_cast<float4*>(&s_x1[0][0]);
        #pragma unroll
        for (int i = 0; i < (ZPB * NSEG0 * U_DIM / 4) / BLK; ++i)   // 8 iters
            l0[i * BLK + t] = g0[i * BLK + t];
        #pragma unroll
        for (int i = 0; i < (ZPB * NSEG1 * U_DIM / 4) / BLK; ++i)   // 2 iters
            l1[i * BLK + t] = g1[i * BLK + t];
    }
    __syncthreads();

    // --- parallel grouping by output segment (order within a segment is free) ---
    int my_rank = 0;
    if (t < P_DIM) my_rank = atomicAdd(&s_cnt[my_o], 1);
    __syncthreads();
    if (t < NSEG2) {                 // exclusive prefix over 32 counts
        int sum = 0;
        for (int o = 0; o < t; ++o) sum += s_cnt[o];
        s_off[t] = sum;
    }
    __syncthreads();
    if (t < P_DIM) {
        const int d = s_off[my_o] + my_rank;
        s_pack[d] = my_i0 | (my_i1 << 16);
        s_c[d]    = my_c;
    }
    __syncthreads();

    // --- compute: thread = (z_local, u); wave = 64 consecutive u of one z ---
    const int zl = t >> 7;           // 0..ZPB-1
    const int u  = t & 127;
    const float* x0z = &s_x0[zl][0];
    const float* x1z = &s_x1[zl][0];
    const size_t z = (size_t)blockIdx.x * ZPB + zl;
    float* orow = out + z * (NSEG2 * U_DIM) + u;

    int b = 0;
    for (int o = 0; o < NSEG2; ++o) {
        const int e = b + s_cnt[o];  // uniform bounds -> no divergence
        float acc = 0.f;
        for (int k = b; k < e; ++k) {
            const int   pk = s_pack[k];          // uniform broadcast reads
            const float c  = s_c[k];
            const float a  = x0z[(pk & 0xffff) * U_DIM + u];
            const float v  = x1z[(pk >> 16)    * U_DIM + u];
            acc = fmaf(c, a * v, acc);
        }
        orow[o * U_DIM] = acc;       // coalesced dword store
        b = e;
    }
}

extern "C" void kernel_launch(void* const* d_in, const int* in_sizes, int n_in,
                              void* d_out, int out_size, void* d_ws, size_t ws_size,
                              hipStream_t stream) {
    const float* x0      = (const float*)d_in[0];
    const float* x1      = (const float*)d_in[1];
    const float* coeffs  = (const float*)d_in[2];
    const int*   idx0    = (const int*)d_in[3];
    const int*   idx1    = (const int*)d_in[4];
    const int*   idx_out = (const int*)d_in[5];
    float* out = (float*)d_out;

    const int blocks = Z_DIM / ZPB;  // 8192
    tp_kernel<<<blocks, BLK, 0, stream>>>(x0, x1, coeffs, idx0, idx1, idx_out, out);
}

// Round 3
// 114.090 us; speedup vs baseline: 2.8101x; 1.5993x over previous
//
#include <hip/hip_runtime.h>

// TensorProduct: out[z, o*U+u] = sum_{p: idx_out[p]==o} coeffs[p] * x0[z, idx0[p]*U+u] * x1[z, idx1[p]*U+u]
// Z=16384, U=128, NSEG=(32,8,32), P=128, all f32.
// Round 2 was LDS/VALU-issue bound (scalar ds_read_b32 per element, VALUBusy 48%).
// Round 3: float4 per thread + ds_read_b128; wave = 4 output segments x (2 z x 32 u-quads);
// BLK=512, ZPB=2 -> ~41 KB LDS -> 3 blocks/CU -> 24 waves/CU.

#define Z_DIM 16384
#define U_DIM 128
#define NSEG0 32
#define NSEG1 8
#define NSEG2 32
#define P_DIM 128
#define ZPB   2
#define BLK   512

__global__ __launch_bounds__(BLK) void tp_kernel(
    const float* __restrict__ x0,
    const float* __restrict__ x1,
    const float* __restrict__ coeffs,
    const int* __restrict__ idx0,
    const int* __restrict__ idx1,
    const int* __restrict__ idx_out,
    float* __restrict__ out)
{
    __shared__ float s_x0[ZPB][NSEG0 * U_DIM];   // 32 KB
    __shared__ float s_x1[ZPB][NSEG1 * U_DIM];   //  8 KB
    __shared__ int2  s_meta[P_DIM];              // (i0|i1<<16, coeff bits), sorted by o
    __shared__ int   s_cnt[NSEG2];
    __shared__ int   s_off[NSEG2];

    const int t = threadIdx.x;

    // --- load this thread's term ---
    int my_o = 0, my_i0 = 0, my_i1 = 0, my_cb = 0;
    if (t < P_DIM) {
        my_o  = idx_out[t];
        my_i0 = idx0[t];
        my_i1 = idx1[t];
        my_cb = __float_as_int(coeffs[t]);
    }
    if (t < NSEG2) s_cnt[t] = 0;

    // --- stage x0/x1 rows (contiguous float4 copy, 5 iters/thread total) ---
    {
        const size_t z0 = (size_t)blockIdx.x * ZPB;
        const float4* g0 = reinterpret_cast<const float4*>(x0 + z0 * (NSEG0 * U_DIM));
        const float4* g1 = reinterpret_cast<const float4*>(x1 + z0 * (NSEG1 * U_DIM));
        float4* l0 = reinterpret_cast<float4*>(&s_x0[0][0]);
        float4* l1 = reinterpret_cast<float4*>(&s_x1[0][0]);
        #pragma unroll
        for (int i = 0; i < (ZPB * NSEG0 * U_DIM / 4) / BLK; ++i)   // 4 iters
            l0[i * BLK + t] = g0[i * BLK + t];
        #pragma unroll
        for (int i = 0; i < (ZPB * NSEG1 * U_DIM / 4) / BLK; ++i)   // 1 iter
            l1[i * BLK + t] = g1[i * BLK + t];
    }
    __syncthreads();

    // --- parallel grouping by output segment ---
    int my_rank = 0;
    if (t < P_DIM) my_rank = atomicAdd(&s_cnt[my_o], 1);
    __syncthreads();
    if (t < NSEG2) {
        int sum = 0;
        for (int o = 0; o < t; ++o) sum += s_cnt[o];
        s_off[t] = sum;
    }
    __syncthreads();
    if (t < P_DIM)
        s_meta[s_off[my_o] + my_rank] = make_int2(my_i0 | (my_i1 << 16), my_cb);
    __syncthreads();

    // --- compute: wave = 4 segments; lanes = (zl in [0,2), uq in [0,32)) ---
    const int wave = t >> 6;          // 0..7 -> segment quarter
    const int zl   = (t >> 5) & 1;
    const int uq   = t & 31;          // float4 column

    const float* x0base = &s_x0[zl][uq * 4];
    const float* x1base = &s_x1[zl][uq * 4];
    const size_t z = (size_t)blockIdx.x * ZPB + zl;
    float4* orow = reinterpret_cast<float4*>(out + z * (NSEG2 * U_DIM)) + uq;

    #pragma unroll
    for (int oo = 0; oo < 4; ++oo) {
        const int o = wave * 4 + oo;
        const int b = s_off[o];
        const int e = b + s_cnt[o];   // wave-uniform bounds
        float4 acc = make_float4(0.f, 0.f, 0.f, 0.f);
        for (int k = b; k < e; ++k) {
            const int2  m = s_meta[k];                 // broadcast ds_read_b64
            const float c = __int_as_float(m.y);
            const float4 a = *reinterpret_cast<const float4*>(x0base + (m.x & 0xffff) * U_DIM);
            const float4 v = *reinterpret_cast<const float4*>(x1base + (m.x >> 16)    * U_DIM);
            acc.x = fmaf(c, a.x * v.x, acc.x);
            acc.y = fmaf(c, a.y * v.y, acc.y);
            acc.z = fmaf(c, a.z * v.z, acc.z);
            acc.w = fmaf(c, a.w * v.w, acc.w);
        }
        orow[o * (U_DIM / 4)] = acc;  // coalesced dwordx4 store
    }
}

extern "C" void kernel_launch(void* const* d_in, const int* in_sizes, int n_in,
                              void* d_out, int out_size, void* d_ws, size_t ws_size,
                              hipStream_t stream) {
    const float* x0      = (const float*)d_in[0];
    const float* x1      = (const float*)d_in[1];
    const float* coeffs  = (const float*)d_in[2];
    const int*   idx0    = (const int*)d_in[3];
    const int*   idx1    = (const int*)d_in[4];
    const int*   idx_out = (const int*)d_in[5];
    float* out = (float*)d_out;

    const int blocks = Z_DIM / ZPB;   // 8192
    tp_kernel<<<blocks, BLK, 0, stream>>>(x0, x1, coeffs, idx0, idx1, idx_out, out);
}